// Round 3
// baseline (1349.649 us; speedup 1.0000x reference)
//
#include <hip/hip_runtime.h>

#define N_NODES 50000
#define N_EDGES 800000
#define R_REL   8
#define NR      (N_NODES * R_REL)        // 400000
#define SCAN_CHUNK 2048
#define SCAN_NBLK  ((NR + SCAN_CHUNK - 1) / SCAN_CHUNK)   // 196

typedef float  f32x4  __attribute__((ext_vector_type(4)));
typedef __bf16 bf16x8 __attribute__((ext_vector_type(8)));

__device__ __forceinline__ unsigned short f2bf(float f) {
    unsigned int u = __float_as_uint(f);
    u = (u + 0x7FFFu + ((u >> 16) & 1u)) >> 16;   // RNE
    return (unsigned short)u;
}
__device__ __forceinline__ float bflo(unsigned int u) { return __uint_as_float(u << 16); }
__device__ __forceinline__ float bfhi(unsigned int u) { return __uint_as_float(u & 0xFFFF0000u); }

// 8 feature atomic-adds into LDS (one uint4 = 8 packed bf16)
__device__ __forceinline__ void at8(float* b, uint4 u) {
    atomicAdd(b + 0, bflo(u.x)); atomicAdd(b + 1, bfhi(u.x));
    atomicAdd(b + 2, bflo(u.y)); atomicAdd(b + 3, bfhi(u.y));
    atomicAdd(b + 4, bflo(u.z)); atomicAdd(b + 5, bfhi(u.z));
    atomicAdd(b + 6, bflo(u.w)); atomicAdd(b + 7, bfhi(u.w));
}

// ---------------- counting-sort CSR build (edge-parallel, no buckets) ----------------

__global__ __launch_bounds__(256) void k_count(
    const int* __restrict__ dst, const int* __restrict__ et,
    int* __restrict__ cnt)
{
    int e = blockIdx.x * 256 + threadIdx.x;
    if (e < N_EDGES) {
        int key = dst[e] * 8 + et[e];
        atomicAdd(&cnt[key], 1);
    }
}

__global__ __launch_bounds__(256) void k_scan1(
    const int* __restrict__ cnt, int* __restrict__ offs, int* __restrict__ bsum)
{
    __shared__ int sd[256];
    int t = threadIdx.x;
    int base = blockIdx.x * SCAN_CHUNK + t * 8;
    int v[8];
    int tot = 0;
#pragma unroll
    for (int i = 0; i < 8; i++) {
        int idx = base + i;
        int xv = (idx < NR) ? cnt[idx] : 0;
        v[i] = tot;
        tot += xv;
    }
    sd[t] = tot;
    __syncthreads();
    for (int off = 1; off < 256; off <<= 1) {
        int y = (t >= off) ? sd[t - off] : 0;
        __syncthreads();
        sd[t] += y;
        __syncthreads();
    }
    int excl = sd[t] - tot;
#pragma unroll
    for (int i = 0; i < 8; i++) {
        int idx = base + i;
        if (idx < NR) offs[idx] = v[i] + excl;
    }
    if (t == 255) bsum[blockIdx.x] = sd[255];
}

// inline 196-entry scan of bsum -> finalize offs chunk + init scatter cursors
__global__ __launch_bounds__(256) void k_scan2fin(
    const int* __restrict__ bsum, int* __restrict__ offs, int* __restrict__ curs)
{
    __shared__ int sd[256];
    __shared__ int sadd;
    int t = threadIdx.x, b = blockIdx.x;
    int v = (t < SCAN_NBLK) ? bsum[t] : 0;
    sd[t] = v;
    __syncthreads();
    for (int off = 1; off < 256; off <<= 1) {
        int y = (t >= off) ? sd[t - off] : 0;
        __syncthreads();
        sd[t] += y;
        __syncthreads();
    }
    if (t == b) sadd = sd[t] - v;     // exclusive prefix at b (b < 196 <= 255)
    __syncthreads();
    const int add = sadd;
    const int base = b * SCAN_CHUNK;
    for (int i = t; i < SCAN_CHUNK; i += 256) {
        int k = base + i;
        if (k < NR) {
            int o = offs[k] + add;
            offs[k] = o;
            curs[k] = o;
        }
    }
    if (b == 0 && t == 0) offs[NR] = N_EDGES;
}

__global__ __launch_bounds__(256) void k_scat(
    const int* __restrict__ src, const int* __restrict__ dst,
    const int* __restrict__ et, int* __restrict__ curs,
    int* __restrict__ srcS)
{
    int e = blockIdx.x * 256 + threadIdx.x;
    if (e < N_EDGES) {
        int key = dst[e] * 8 + et[e];
        int p = atomicAdd(&curs[key], 1);
        srcS[p] = src[e];
    }
}

// ---------------- converts (cvt_x + wprep + cnt-zero fused) ----------------

#define W1_ELEMS (9 * 128 * 128)   // NBt=8
#define W2_ELEMS (9 * 64 * 128)    // NBt=4
#define N4       (N_NODES * 32)    // 1.6M float4 groups

__global__ __launch_bounds__(256) void k_cvtw(
    const float* __restrict__ x, unsigned short* __restrict__ xb,
    const float* __restrict__ root1, const float* __restrict__ W1,
    const float* __restrict__ root2, const float* __restrict__ W2,
    unsigned short* __restrict__ Wt1, unsigned short* __restrict__ Wt2,
    int* __restrict__ cnt)
{
    const int idx = blockIdx.x * 256 + threadIdx.x;
    if (idx < NR) cnt[idx] = 0;            // zero counters for k_count
    if (idx < N4) {
        float4 v = *(const float4*)(x + (size_t)idx * 4);
        ushort4 o;
        o.x = f2bf(v.x); o.y = f2bf(v.y); o.z = f2bf(v.z); o.w = f2bf(v.w);
        *(ushort4*)(xb + (size_t)idx * 4) = o;
    }
    if (idx < W1_ELEMS) {
        int j    = idx & 7;
        int lane = (idx >> 3) & 63;
        int r    = idx >> 9;
        int nb   = r & 7;        // NBt = 8
        int r2   = r >> 3;
        int kk   = r2 & 3;
        int seg  = r2 >> 2;
        int k = kk * 32 + (lane >> 4) * 8 + j;
        int n = nb * 16 + (lane & 15);
        float v = (seg == 0) ? root1[k * 128 + n] : W1[((seg - 1) * 128 + k) * 128 + n];
        Wt1[idx] = f2bf(v);
    } else if (idx < W1_ELEMS + W2_ELEMS) {
        int i2   = idx - W1_ELEMS;
        int j    = i2 & 7;
        int lane = (i2 >> 3) & 63;
        int r    = i2 >> 9;
        int nb   = r & 3;        // NBt = 4
        int r2   = r >> 2;
        int kk   = r2 & 3;
        int seg  = r2 >> 2;
        int k = kk * 32 + (lane >> 4) * 8 + j;
        int n = nb * 16 + (lane & 15);
        float v = (seg == 0) ? root2[k * 64 + n] : W2[((seg - 1) * 128 + k) * 64 + n];
        Wt2[i2] = f2bf(v);
    }
}

// ---------------- fused gather + MFMA layer (edge-parallel, LDS f32 atomics) ----------------
// Round-2 evidence: chain-gather is MLP/latency-bound (conflict fix moved the
// counter, not the time; round-1 halving in-flight bytes cost 29%). This version
// eliminates chains: after a cheap key-expansion (threads 0-127 write a u8 key
// per edge), all 512 threads process (edge, 32-feat-quarter) tasks work-balanced
// -- ~2 tasks/thread, 8 uint4 always in flight, no stragglers -- and accumulate
// via ds_add_f32 into accumF[key][4][33] (pad 33: atomic bank = 4k+q+f -> ~2-way
// with random keys; readback = exactly 2-way = free). accumF (66 KB) is overlaid
// by the bf16 As[1..8] slabs after a register bounce, so LDS = 71 KB -> 2
// blocks/CU. MFMA phase identical to round 2 (proven): fragment-ordered B,
// XOR-swizzled A-slab granules.

template <int FOUT, bool RELU, bool OUT_BF16>
__global__ __launch_bounds__(512) void k_fused(
    const unsigned short* __restrict__ xin,  // [N,128] bf16
    const unsigned short* __restrict__ WtP,  // fragment-ordered weights
    const float* __restrict__ bias,          // [FOUT]
    const int* __restrict__ offs,            // [NR+1]
    const int* __restrict__ srcS,            // [E]
    unsigned short* __restrict__ outb,       // [N,FOUT] bf16 (if OUT_BF16)
    float* __restrict__ outf)                // [N,FOUT] fp32 (else)
{
    constexpr int NBt = FOUT / 16;           // 8 (L1) / 4 (L2)
    __shared__ __align__(16) float accumF[128 * 132];       // 67584 B; As[1..8] overlays
    __shared__ __align__(16) unsigned short As0[16][136];   // 4352 B (root slab)
    __shared__ unsigned char kbuf[640];                     // per-edge key (24 sigma cap)
    __shared__ unsigned short degb[128];                    // per-key degree

    const int t = threadIdx.x;
    const int node0 = blockIdx.x * 16;
    const int pair0 = node0 * 8;

    // ---- P0: zero accum + stage seg0 + expand keys ----
#pragma unroll
    for (int i = 0; i < 33; ++i) accumF[t + i * 512] = 0.f;   // 16896 = 33*512 exact

    if (t < 128) {
        const int sr = t >> 3;
        const int sp = t & 7;
        const uint4* s4 = (const uint4*)(xin + (size_t)(node0 + sr) * 128 + sp * 16);
        uint4 r0 = s4[0], r1 = s4[1];
        uint4* d = (uint4*)&As0[sr][sp * 16];
        d[0] = r0; d[1] = r1;
    }

    const int e0 = offs[pair0];          // block-uniform
    const int e1 = offs[pair0 + 128];
    if (t < 128) {
        int beg = offs[pair0 + t];
        int end = offs[pair0 + t + 1];
        degb[t] = (unsigned short)(end - beg);
        for (int j = beg; j < end; ++j) kbuf[j - e0] = (unsigned char)t;
    }
    __syncthreads();   // bar1: accum zeroed, kbuf/degb/As0 ready

    // ---- P2: edge-parallel gather + LDS f32 atomics (2 tasks in flight) ----
    const int NTASK = (e1 - e0) * 4;
    for (int i = t; i < NTASK; i += 1024) {
        const int ea = i >> 2, qa = i & 3;
        const int sa = srcS[e0 + ea];
        const int ka = kbuf[ea];
        const uint4* pa = (const uint4*)(xin + (size_t)sa * 128 + qa * 32);
        uint4 a0 = pa[0], a1 = pa[1], a2 = pa[2], a3 = pa[3];

        const int ib = i + 512;
        const bool vb = ib < NTASK;
        uint4 b0, b1, b2, b3;
        int kb = 0, qb = 0;
        if (vb) {
            const int ebi = ib >> 2; qb = ib & 3;
            const int sb = srcS[e0 + ebi];
            kb = kbuf[ebi];
            const uint4* pb = (const uint4*)(xin + (size_t)sb * 128 + qb * 32);
            b0 = pb[0]; b1 = pb[1]; b2 = pb[2]; b3 = pb[3];
        }

        float* ba = accumF + ka * 132 + qa * 33;
        at8(ba, a0); at8(ba + 8, a1); at8(ba + 16, a2); at8(ba + 24, a3);
        if (vb) {
            float* bb = accumF + kb * 132 + qb * 33;
            at8(bb, b0); at8(bb + 8, b1); at8(bb + 16, b2); at8(bb + 24, b3);
        }
    }
    __syncthreads();   // bar2: all atomics done

    // ---- P3: accum -> registers (scale + pack to bf16) ----
    const int key = t >> 2;        // (nl*8 + rel)
    const int q   = t & 3;
    const int deg = degb[key];
    const float scl = 1.f / (float)(deg > 1 ? deg : 1);
    const float* rp = accumF + key * 132 + q * 33;
    unsigned int pk[16];
#pragma unroll
    for (int i = 0; i < 16; ++i) {
        float lo = rp[2 * i]     * scl;
        float hi = rp[2 * i + 1] * scl;
        pk[i] = (unsigned int)f2bf(lo) | ((unsigned int)f2bf(hi) << 16);
    }
    __syncthreads();   // bar3: all reads done before overlay writes

    // ---- P3b: write As[1..8] slabs over accumF, round-2 XOR-swizzled granules ----
    {
        const int nl  = key >> 3;
        const int rel = key & 7;
        uint4* G = (uint4*)((unsigned short*)accumF + (size_t)(rel * 16 + nl) * 136);
        const int g0 = q * 4;
        G[(g0 + 0) ^ rel] = make_uint4(pk[0],  pk[1],  pk[2],  pk[3]);
        G[(g0 + 1) ^ rel] = make_uint4(pk[4],  pk[5],  pk[6],  pk[7]);
        G[(g0 + 2) ^ rel] = make_uint4(pk[8],  pk[9],  pk[10], pk[11]);
        G[(g0 + 3) ^ rel] = make_uint4(pk[12], pk[13], pk[14], pk[15]);
    }
    __syncthreads();   // bar4: slabs ready

    // ---- P4: MFMA, wave w owns col-tile w (identical math to round 2) ----
    const int lane = t & 63;
    const int w = t >> 6;
    if (w >= NBt) return;            // FOUT=64: waves 4-7 done (no barriers after)
    const int quad = lane >> 4;
    const int tc = lane & 15;

    f32x4 acc = (f32x4){0.f, 0.f, 0.f, 0.f};
    const bf16x8* Bp = (const bf16x8*)WtP;

#pragma unroll
    for (int seg = 0; seg < 9; ++seg) {
        const uint4* Ag = (seg == 0)
            ? (const uint4*)&As0[tc][0]
            : (const uint4*)((const unsigned short*)accumF + (size_t)((seg - 1) * 16 + tc) * 136);
        const int s = (seg == 0) ? 0 : (seg - 1);   // un-swizzle (uniform per instr)
#pragma unroll
        for (int kk = 0; kk < 4; ++kk) {
            bf16x8 af = *(const bf16x8*)(Ag + (((kk << 2) + quad) ^ s));
            bf16x8 bf = Bp[((seg * 4 + kk) * NBt + w) * 64 + lane];
            acc = __builtin_amdgcn_mfma_f32_16x16x32_bf16(af, bf, acc, 0, 0, 0);
        }
    }

    // epilogue: D layout col = lane&15, row = quad*4 + reg
    const int col = w * 16 + tc;
    const float bs = bias[col];
#pragma unroll
    for (int i = 0; i < 4; ++i) {
        int r = node0 + quad * 4 + i;
        float v = acc[i] + bs;
        if (RELU) v = fmaxf(v, 0.f);
        if (OUT_BF16) outb[(size_t)r * FOUT + col] = f2bf(v);
        else          outf[(size_t)r * FOUT + col] = v;
    }
}

// ---------------- launch ----------------

extern "C" void kernel_launch(void* const* d_in, const int* in_sizes, int n_in,
                              void* d_out, int out_size, void* d_ws, size_t ws_size,
                              hipStream_t stream) {
    const float* x     = (const float*)d_in[0];
    const int*   ei    = (const int*)d_in[1];  // [2][E]: row0=src, row1=dst
    const int*   et    = (const int*)d_in[2];  // [E]
    const float* W1    = (const float*)d_in[3];
    const float* root1 = (const float*)d_in[4];
    const float* b1    = (const float*)d_in[5];
    const float* W2    = (const float*)d_in[6];
    const float* root2 = (const float*)d_in[7];
    const float* b2    = (const float*)d_in[8];
    float* out = (float*)d_out;

    int* ws   = (int*)d_ws;
    int* cnt  = ws;                    // [NR]
    int* offs = cnt + NR;              // [NR+1] (+pad)
    int* curs = offs + NR + 128;       // [NR]
    int* bsum = curs + NR;             // [256]
    int* srcS = bsum + 256;            // [E]
    unsigned short* xb  = (unsigned short*)(srcS + N_EDGES); // [N,128] bf16 (12.8 MB)
    unsigned short* hb  = xb + (size_t)N_NODES * 128;        // [N,128] bf16 (12.8 MB)
    unsigned short* Wt1 = hb + (size_t)N_NODES * 128;        // W1_ELEMS shorts
    unsigned short* Wt2 = Wt1 + W1_ELEMS;                    // W2_ELEMS shorts
    // total ws usage: ~8 MB ints + 12.8 + 12.8 + 0.9 = ~35 MB (ws = 256 MiB)

    const int* esrc = ei;
    const int* edst = ei + N_EDGES;

    // 7 dispatches, all fully parallel (no bucket kernels, no gbin round trip)
    k_cvtw<<<(N4 + 255) / 256, 256, 0, stream>>>(x, xb, root1, W1, root2, W2,
                                                 Wt1, Wt2, cnt);
    k_count<<<(N_EDGES + 255) / 256, 256, 0, stream>>>(edst, et, cnt);
    k_scan1<<<SCAN_NBLK, 256, 0, stream>>>(cnt, offs, bsum);
    k_scan2fin<<<SCAN_NBLK, 256, 0, stream>>>(bsum, offs, curs);
    k_scat<<<(N_EDGES + 255) / 256, 256, 0, stream>>>(esrc, edst, et, curs, srcS);

    const int NT = N_NODES / 16;  // 3125 exactly

    k_fused<128, true,  true ><<<NT, 512, 0, stream>>>(xb, Wt1, b1, offs, srcS, hb, nullptr);
    k_fused<64,  false, false><<<NT, 512, 0, stream>>>(hb, Wt2, b2, offs, srcS, nullptr, out);
}

// Round 4
// 254.648 us; speedup vs baseline: 5.3001x; 5.3001x over previous
//
#include <hip/hip_runtime.h>

#define N_NODES 50000
#define N_EDGES 800000
#define R_REL   8

// per-dst-tile binning (16 nodes per tile == fused block tile)
#define TNBKT   3125                     // 50000/16 bins
#define TCAP    512                      // records per bin (mean 256, +16 sigma)
#define SLAB    2048                     // edges per bin-block
#define BINBLK  ((N_EDGES + SLAB - 1) / SLAB)  // 391

typedef float  f32x4  __attribute__((ext_vector_type(4)));
typedef __bf16 bf16x8 __attribute__((ext_vector_type(8)));

__device__ __forceinline__ unsigned short f2bf(float f) {
    unsigned int u = __float_as_uint(f);
    u = (u + 0x7FFFu + ((u >> 16) & 1u)) >> 16;   // RNE
    return (unsigned short)u;
}
__device__ __forceinline__ float bflo(unsigned int u) { return __uint_as_float(u << 16); }
__device__ __forceinline__ float bfhi(unsigned int u) { return __uint_as_float(u & 0xFFFF0000u); }

__device__ __forceinline__ void acc16(float* a, uint4 u0, uint4 u1) {
    a[0]  += bflo(u0.x);   a[1]  += bfhi(u0.x);
    a[2]  += bflo(u0.y);   a[3]  += bfhi(u0.y);
    a[4]  += bflo(u0.z);   a[5]  += bfhi(u0.z);
    a[6]  += bflo(u0.w);   a[7]  += bfhi(u0.w);
    a[8]  += bflo(u1.x);   a[9]  += bfhi(u1.x);
    a[10] += bflo(u1.y);   a[11] += bfhi(u1.y);
    a[12] += bflo(u1.z);   a[13] += bfhi(u1.z);
    a[14] += bflo(u1.w);   a[15] += bfhi(u1.w);
}

// ---------------- one-pass dst-tile binning (record = src<<7 | localkey) ----------------
// Mirror of the proven k_binA: LDS histogram -> one global atomic per nonzero
// bin -> LDS sub-cursor scatter. Record is 4B (src fits u16: 50000 < 65536;
// localkey = (dst&15)*8+rel fits 7b). No global CSR, no scans, no srcS.

__global__ __launch_bounds__(256) void k_bin(
    const int* __restrict__ src, const int* __restrict__ dst,
    const int* __restrict__ et, int* __restrict__ gcur,
    unsigned* __restrict__ gbin)
{
    __shared__ int hist[TNBKT];
    __shared__ int base[TNBKT];
    const int t = threadIdx.x;
    const int e0 = blockIdx.x * SLAB;
    for (int i = t; i < TNBKT; i += 256) hist[i] = 0;
    __syncthreads();
#pragma unroll
    for (int i = 0; i < SLAB / 256; ++i) {
        int e = e0 + i * 256 + t;
        if (e < N_EDGES) atomicAdd(&hist[dst[e] >> 4], 1);
    }
    __syncthreads();
    for (int i = t; i < TNBKT; i += 256) {
        int h = hist[i];
        base[i] = (h > 0) ? atomicAdd(&gcur[i], h) : 0;
        hist[i] = 0;   // reuse as sub-cursor
    }
    __syncthreads();
#pragma unroll
    for (int i = 0; i < SLAB / 256; ++i) {
        int e = e0 + i * 256 + t;
        if (e < N_EDGES) {
            int d = dst[e];
            int b = d >> 4;
            int sub = atomicAdd(&hist[b], 1);
            int pos = base[b] + sub;
            unsigned rec = ((unsigned)src[e] << 7) | (unsigned)((d & 15) * 8 + et[e]);
            if (pos < TCAP) gbin[(size_t)b * TCAP + pos] = rec;
        }
    }
}

// ---------------- converts (cvt_x + wprep + gcur-zero fused) ----------------

#define W1_ELEMS (9 * 128 * 128)   // NBt=8
#define W2_ELEMS (9 * 64 * 128)    // NBt=4
#define N4       (N_NODES * 32)    // 1.6M float4 groups

__global__ __launch_bounds__(256) void k_cvtw(
    const float* __restrict__ x, unsigned short* __restrict__ xb,
    const float* __restrict__ root1, const float* __restrict__ W1,
    const float* __restrict__ root2, const float* __restrict__ W2,
    unsigned short* __restrict__ Wt1, unsigned short* __restrict__ Wt2,
    int* __restrict__ gcur)
{
    const int idx = blockIdx.x * 256 + threadIdx.x;
    if (idx < TNBKT) gcur[idx] = 0;        // zero bin cursors for k_bin
    if (idx < N4) {
        float4 v = *(const float4*)(x + (size_t)idx * 4);
        ushort4 o;
        o.x = f2bf(v.x); o.y = f2bf(v.y); o.z = f2bf(v.z); o.w = f2bf(v.w);
        *(ushort4*)(xb + (size_t)idx * 4) = o;
    }
    if (idx < W1_ELEMS) {
        int j    = idx & 7;
        int lane = (idx >> 3) & 63;
        int r    = idx >> 9;
        int nb   = r & 7;        // NBt = 8
        int r2   = r >> 3;
        int kk   = r2 & 3;
        int seg  = r2 >> 2;
        int k = kk * 32 + (lane >> 4) * 8 + j;
        int n = nb * 16 + (lane & 15);
        float v = (seg == 0) ? root1[k * 128 + n] : W1[((seg - 1) * 128 + k) * 128 + n];
        Wt1[idx] = f2bf(v);
    } else if (idx < W1_ELEMS + W2_ELEMS) {
        int i2   = idx - W1_ELEMS;
        int j    = i2 & 7;
        int lane = (i2 >> 3) & 63;
        int r    = i2 >> 9;
        int nb   = r & 3;        // NBt = 4
        int r2   = r >> 2;
        int kk   = r2 & 3;
        int seg  = r2 >> 2;
        int k = kk * 32 + (lane >> 4) * 8 + j;
        int n = nb * 16 + (lane & 15);
        float v = (seg == 0) ? root2[k * 64 + n] : W2[((seg - 1) * 128 + k) * 64 + n];
        Wt2[i2] = f2bf(v);
    }
}

// ---------------- fused: in-LDS CSR build + gather + MFMA ----------------
// Round-2's proven gather/MFMA (77.5 us, latency-wall-bound), but the per-tile
// edge list comes from gbin (one ~1KB contiguous read) and the 128-key CSR is
// built in LDS: histogram -> wave-0 shfl scan -> LDS scatter. Kills the global
// scan/scatter preprocessing AND the offs/srcS dependent-load chain head.
// Gather: thread = (node, rel, 32-feat quarter), 2-edge ILP, 8 uint4 in
// flight; src indices now ds_read from sorted[] (broadcast across 4 lanes).
// A-slab writes XOR-swizzled at 16B granules (^rel), MFMA un-XORs (uniform).

template <int FOUT, bool RELU, bool OUT_BF16>
__global__ __launch_bounds__(512) void k_fused(
    const unsigned short* __restrict__ xin,  // [N,128] bf16
    const unsigned short* __restrict__ WtP,  // fragment-ordered weights
    const float* __restrict__ bias,          // [FOUT]
    const int* __restrict__ gcnt,            // [TNBKT] bin counts
    const unsigned* __restrict__ gbin,       // [TNBKT][TCAP] records
    unsigned short* __restrict__ outb,       // [N,FOUT] bf16 (if OUT_BF16)
    float* __restrict__ outf)                // [N,FOUT] fp32 (else)
{
    constexpr int NBt = FOUT / 16;           // 8 (L1) / 4 (L2)
    __shared__ __align__(16) unsigned short As0[16][136];      // 4.25 KB (root)
    __shared__ __align__(16) unsigned short As[8][16][136];    // 34 KB
    __shared__ unsigned short sorted[TCAP];                    // 1 KB src16 by key
    __shared__ int dcnt[128];                                  // per-key degree
    __shared__ int kbeg[128];                                  // per-key begin
    __shared__ int kcur[128];                                  // scatter cursors

    const int t = threadIdx.x;
    const int node0 = blockIdx.x * 16;

    // ---- P0: zero counters, stage seg0, read my bin record ----
    if (t < 128) { dcnt[t] = 0; kcur[t] = 0; }
    if (t < 128) {
        const int sr = t >> 3;
        const int sp = t & 7;
        const uint4* s4 = (const uint4*)(xin + (size_t)(node0 + sr) * 128 + sp * 16);
        uint4 r0 = s4[0], r1 = s4[1];
        uint4* d = (uint4*)&As0[sr][sp * 16];
        d[0] = r0; d[1] = r1;
    }
    const int nraw = gcnt[blockIdx.x];
    const int n = nraw < TCAP ? nraw : TCAP;
    unsigned rec = 0;
    if (t < n) rec = gbin[(size_t)blockIdx.x * TCAP + t];
    __syncthreads();   // bar1: zeros visible

    // ---- P1: per-key histogram ----
    if (t < n) atomicAdd(&dcnt[rec & 127], 1);
    __syncthreads();   // bar2

    // ---- P2: wave-0 exclusive scan over 128 keys (no block barriers inside) ----
    if (t < 64) {
        int d0 = dcnt[2 * t], d1 = dcnt[2 * t + 1];
        int s = d0 + d1;
        int inc = s;
#pragma unroll
        for (int off = 1; off < 64; off <<= 1) {
            int y = __shfl_up(inc, off, 64);
            if (t >= off) inc += y;
        }
        int excl = inc - s;
        kbeg[2 * t]     = excl;
        kbeg[2 * t + 1] = excl + d0;
    }
    __syncthreads();   // bar3

    // ---- P3: scatter-sort records into per-key src lists ----
    if (t < n) {
        int key = rec & 127;
        int pos = atomicAdd(&kcur[key], 1);
        sorted[kbeg[key] + pos] = (unsigned short)(rec >> 7);
    }
    __syncthreads();   // bar4: sorted/dcnt/kbeg ready

    // ---- P4: gather, one chain per (node, rel), 4 lanes (32-feat quarters) ----
    {
        const int key = t >> 2;        // nl*8 + rel
        const int q   = t & 3;         // 32-feat quarter
        const int rel = key & 7;
        const int nl  = key >> 3;

        const int beg = kbeg[key];
        const int deg = dcnt[key];
        const int end = beg + deg;

        const unsigned short* bx = xin + q * 32;
        float a[32];
#pragma unroll
        for (int i = 0; i < 32; ++i) a[i] = 0.f;

        int j = beg;
        for (; j + 1 < end; j += 2) {
            int s0 = sorted[j];
            int s1 = sorted[j + 1];
            const uint4* p0 = (const uint4*)(bx + (size_t)s0 * 128);
            const uint4* p1 = (const uint4*)(bx + (size_t)s1 * 128);
            uint4 v0 = p0[0], v1 = p0[1], v2 = p0[2], v3 = p0[3];
            uint4 w0 = p1[0], w1 = p1[1], w2 = p1[2], w3 = p1[3];
            acc16(a, v0, v1);
            acc16(a + 16, v2, v3);
            acc16(a, w0, w1);
            acc16(a + 16, w2, w3);
        }
        if (j < end) {
            int s = sorted[j];
            const uint4* p = (const uint4*)(bx + (size_t)s * 128);
            uint4 v0 = p[0], v1 = p[1], v2 = p[2], v3 = p[3];
            acc16(a, v0, v1);
            acc16(a + 16, v2, v3);
        }

        float scl = 1.f / (float)(deg > 1 ? deg : 1);
        unsigned int pk[16];
#pragma unroll
        for (int i = 0; i < 16; ++i)
            pk[i] = (unsigned int)f2bf(a[i * 2] * scl) |
                    ((unsigned int)f2bf(a[i * 2 + 1] * scl) << 16);
        // swizzled stores: row-local granule (q*4+i) ^ rel
        uint4* G = (uint4*)&As[rel][nl][0];
        const int g0 = q * 4;
        G[(g0 + 0) ^ rel] = make_uint4(pk[0],  pk[1],  pk[2],  pk[3]);
        G[(g0 + 1) ^ rel] = make_uint4(pk[4],  pk[5],  pk[6],  pk[7]);
        G[(g0 + 2) ^ rel] = make_uint4(pk[8],  pk[9],  pk[10], pk[11]);
        G[(g0 + 3) ^ rel] = make_uint4(pk[12], pk[13], pk[14], pk[15]);
    }

    __syncthreads();   // bar5: all 9 A slabs ready

    // ---- P5: MFMA, wave w owns col-tile w (identical math to round 2) ----
    const int lane = t & 63;
    const int w = t >> 6;
    if (w >= NBt) return;            // FOUT=64: waves 4-7 done (no barriers after)
    const int quad = lane >> 4;
    const int tc = lane & 15;

    f32x4 acc = (f32x4){0.f, 0.f, 0.f, 0.f};
    const bf16x8* Bp = (const bf16x8*)WtP;

#pragma unroll
    for (int seg = 0; seg < 9; ++seg) {
        const uint4* Ag = (seg == 0) ? (const uint4*)&As0[tc][0]
                                     : (const uint4*)&As[seg - 1][tc][0];
        const int s = (seg == 0) ? 0 : (seg - 1);   // un-swizzle (uniform per instr)
#pragma unroll
        for (int kk = 0; kk < 4; ++kk) {
            bf16x8 af = *(const bf16x8*)(Ag + (((kk << 2) + quad) ^ s));
            bf16x8 bf = Bp[((seg * 4 + kk) * NBt + w) * 64 + lane];
            acc = __builtin_amdgcn_mfma_f32_16x16x32_bf16(af, bf, acc, 0, 0, 0);
        }
    }

    // epilogue: D layout col = lane&15, row = quad*4 + reg
    const int col = w * 16 + tc;
    const float bs = bias[col];
#pragma unroll
    for (int i = 0; i < 4; ++i) {
        int r = node0 + quad * 4 + i;
        float v = acc[i] + bs;
        if (RELU) v = fmaxf(v, 0.f);
        if (OUT_BF16) outb[(size_t)r * FOUT + col] = f2bf(v);
        else          outf[(size_t)r * FOUT + col] = v;
    }
}

// ---------------- launch ----------------

extern "C" void kernel_launch(void* const* d_in, const int* in_sizes, int n_in,
                              void* d_out, int out_size, void* d_ws, size_t ws_size,
                              hipStream_t stream) {
    const float* x     = (const float*)d_in[0];
    const int*   ei    = (const int*)d_in[1];  // [2][E]: row0=src, row1=dst
    const int*   et    = (const int*)d_in[2];  // [E]
    const float* W1    = (const float*)d_in[3];
    const float* root1 = (const float*)d_in[4];
    const float* b1    = (const float*)d_in[5];
    const float* W2    = (const float*)d_in[6];
    const float* root2 = (const float*)d_in[7];
    const float* b2    = (const float*)d_in[8];
    float* out = (float*)d_out;

    int* ws = (int*)d_ws;
    int* gcur = ws;                                   // [3200] (TNBKT padded)
    unsigned* gbin = (unsigned*)(gcur + 3200);        // TNBKT*TCAP u32 = 6.4 MB
    unsigned short* xb  = (unsigned short*)(gbin + (size_t)TNBKT * TCAP); // 12.8 MB
    unsigned short* hb  = xb + (size_t)N_NODES * 128;                     // 12.8 MB
    unsigned short* Wt1 = hb + (size_t)N_NODES * 128;                     // 288 KB
    unsigned short* Wt2 = Wt1 + W1_ELEMS;                                 // 144 KB
    // total ws usage ~32.5 MB (ws = 256 MiB)

    const int* esrc = ei;
    const int* edst = ei + N_EDGES;

    // 4 dispatches total: cvt/wprep/zero -> bin -> fused x2 (no global CSR)
    k_cvtw<<<(N4 + 255) / 256, 256, 0, stream>>>(x, xb, root1, W1, root2, W2,
                                                 Wt1, Wt2, gcur);
    k_bin<<<BINBLK, 256, 0, stream>>>(esrc, edst, et, gcur, gbin);

    const int NT = N_NODES / 16;  // 3125 exactly

    k_fused<128, true,  true ><<<NT, 512, 0, stream>>>(xb, Wt1, b1, gcur, gbin, hb, nullptr);
    k_fused<64,  false, false><<<NT, 512, 0, stream>>>(hb, Wt2, b2, gcur, gbin, nullptr, out);
}

// Round 5
// 251.764 us; speedup vs baseline: 5.3608x; 1.0115x over previous
//
#include <hip/hip_runtime.h>

#define N_NODES 50000
#define N_EDGES 800000
#define R_REL   8

// per-dst-tile binning (16 nodes per tile == fused block tile)
#define TNBKT   3125                     // 50000/16 bins
#define TCAP    512                      // records per bin (mean 256, +16 sigma)
#define SLAB    2048                     // edges per bin-block
#define BINBLK  ((N_EDGES + SLAB - 1) / SLAB)  // 391

typedef float  f32x4  __attribute__((ext_vector_type(4)));
typedef __bf16 bf16x8 __attribute__((ext_vector_type(8)));

__device__ __forceinline__ unsigned short f2bf(float f) {
    unsigned int u = __float_as_uint(f);
    u = (u + 0x7FFFu + ((u >> 16) & 1u)) >> 16;   // RNE
    return (unsigned short)u;
}
__device__ __forceinline__ float bflo(unsigned int u) { return __uint_as_float(u << 16); }
__device__ __forceinline__ float bfhi(unsigned int u) { return __uint_as_float(u & 0xFFFF0000u); }

__device__ __forceinline__ void acc16(float* a, uint4 u0, uint4 u1) {
    a[0]  += bflo(u0.x);   a[1]  += bfhi(u0.x);
    a[2]  += bflo(u0.y);   a[3]  += bfhi(u0.y);
    a[4]  += bflo(u0.z);   a[5]  += bfhi(u0.z);
    a[6]  += bflo(u0.w);   a[7]  += bfhi(u0.w);
    a[8]  += bflo(u1.x);   a[9]  += bfhi(u1.x);
    a[10] += bflo(u1.y);   a[11] += bfhi(u1.y);
    a[12] += bflo(u1.z);   a[13] += bfhi(u1.z);
    a[14] += bflo(u1.w);   a[15] += bfhi(u1.w);
}

// ---------------- merged prep: dst-tile binning + converts in ONE dispatch ----------------
// Blocks [0, BINBLK) bin edges to dst-tiles (record = src<<7 | localkey, 4B).
// Blocks [BINBLK, ...) do x->bf16 convert + fragment-ordered weight packing.
// The 391 latency-heavy bin blocks now overlap the BW-bound convert stream
// instead of serializing behind it in a separate dispatch.

#define W1_ELEMS (9 * 128 * 128)   // NBt=8
#define W2_ELEMS (9 * 64 * 128)    // NBt=4
#define N4       (N_NODES * 32)    // 1.6M float4 groups
#define NB_CVT   ((N4 + 255) / 256)            // 6250
#define NB_PREP  (BINBLK + NB_CVT)             // 6641

__global__ __launch_bounds__(256) void k_prep(
    const int* __restrict__ src, const int* __restrict__ dst,
    const int* __restrict__ et, int* __restrict__ gcur,
    unsigned* __restrict__ gbin,
    const float* __restrict__ x, unsigned short* __restrict__ xb,
    const float* __restrict__ root1, const float* __restrict__ W1,
    const float* __restrict__ root2, const float* __restrict__ W2,
    unsigned short* __restrict__ Wt1, unsigned short* __restrict__ Wt2)
{
    __shared__ int hist[TNBKT];
    __shared__ int base[TNBKT];
    const int t = threadIdx.x;

    if (blockIdx.x < BINBLK) {
        // ---------- bin branch ----------
        const int e0 = blockIdx.x * SLAB;
        for (int i = t; i < TNBKT; i += 256) hist[i] = 0;
        __syncthreads();
#pragma unroll
        for (int i = 0; i < SLAB / 256; ++i) {
            int e = e0 + i * 256 + t;
            if (e < N_EDGES) atomicAdd(&hist[dst[e] >> 4], 1);
        }
        __syncthreads();
        for (int i = t; i < TNBKT; i += 256) {
            int h = hist[i];
            base[i] = (h > 0) ? atomicAdd(&gcur[i], h) : 0;
            hist[i] = 0;   // reuse as sub-cursor
        }
        __syncthreads();
#pragma unroll
        for (int i = 0; i < SLAB / 256; ++i) {
            int e = e0 + i * 256 + t;
            if (e < N_EDGES) {
                int d = dst[e];
                int b = d >> 4;
                int sub = atomicAdd(&hist[b], 1);
                int pos = base[b] + sub;
                unsigned rec = ((unsigned)src[e] << 7) | (unsigned)((d & 15) * 8 + et[e]);
                if (pos < TCAP) gbin[(size_t)b * TCAP + pos] = rec;
            }
        }
        return;
    }

    // ---------- convert branch ----------
    const int idx = (blockIdx.x - BINBLK) * 256 + t;
    if (idx < N4) {
        float4 v = *(const float4*)(x + (size_t)idx * 4);
        ushort4 o;
        o.x = f2bf(v.x); o.y = f2bf(v.y); o.z = f2bf(v.z); o.w = f2bf(v.w);
        *(ushort4*)(xb + (size_t)idx * 4) = o;
    }
    if (idx < W1_ELEMS) {
        int j    = idx & 7;
        int lane = (idx >> 3) & 63;
        int r    = idx >> 9;
        int nb   = r & 7;        // NBt = 8
        int r2   = r >> 3;
        int kk   = r2 & 3;
        int seg  = r2 >> 2;
        int k = kk * 32 + (lane >> 4) * 8 + j;
        int n = nb * 16 + (lane & 15);
        float v = (seg == 0) ? root1[k * 128 + n] : W1[((seg - 1) * 128 + k) * 128 + n];
        Wt1[idx] = f2bf(v);
    } else if (idx < W1_ELEMS + W2_ELEMS) {
        int i2   = idx - W1_ELEMS;
        int j    = i2 & 7;
        int lane = (i2 >> 3) & 63;
        int r    = i2 >> 9;
        int nb   = r & 3;        // NBt = 4
        int r2   = r >> 2;
        int kk   = r2 & 3;
        int seg  = r2 >> 2;
        int k = kk * 32 + (lane >> 4) * 8 + j;
        int n = nb * 16 + (lane & 15);
        float v = (seg == 0) ? root2[k * 64 + n] : W2[((seg - 1) * 128 + k) * 64 + n];
        Wt2[i2] = f2bf(v);
    }
}

// ---------------- fused: in-LDS CSR build + pipelined gather + MFMA ----------------
// Round-4 structure (in-LDS CSR from gbin, proven neutral) + the round-5 change:
// depth-2 SOFTWARE-PIPELINED gather. Old loop: load 8 uint4 -> wait -> ~280cy
// VALU with ZERO loads in flight -> repeat (measured ~25 outstanding lines/CU
// vs ~45 to saturate; VALUBusy 36%, all pipes idle => MLP-bound). New loop
// prefetches the NEXT 2-edge group's 8 uint4 before accumulating the current
// group, keeping loads in flight through the VALU phase. Prefetch is branchless:
// sorted[] is zero-padded, so over-reads clamp to row 0 (L1-hot). ~+40 VGPR,
// fine at the measured ~12 waves/CU residency.

template <int FOUT, bool RELU, bool OUT_BF16>
__global__ __launch_bounds__(512) void k_fused(
    const unsigned short* __restrict__ xin,  // [N,128] bf16
    const unsigned short* __restrict__ WtP,  // fragment-ordered weights
    const float* __restrict__ bias,          // [FOUT]
    const int* __restrict__ gcnt,            // [TNBKT] bin counts
    const unsigned* __restrict__ gbin,       // [TNBKT][TCAP] records
    unsigned short* __restrict__ outb,       // [N,FOUT] bf16 (if OUT_BF16)
    float* __restrict__ outf)                // [N,FOUT] fp32 (else)
{
    constexpr int NBt = FOUT / 16;           // 8 (L1) / 4 (L2)
    __shared__ __align__(16) unsigned short As0[16][136];      // 4.25 KB (root)
    __shared__ __align__(16) unsigned short As[8][16][136];    // 34 KB
    __shared__ unsigned short sorted[TCAP + 8];                // zero-padded
    __shared__ int dcnt[128];                                  // per-key degree
    __shared__ int kbeg[128];                                  // per-key begin
    __shared__ int kcur[128];                                  // scatter cursors

    const int t = threadIdx.x;
    const int node0 = blockIdx.x * 16;

    // ---- P0: zero counters + sorted pad, stage seg0, read my bin record ----
    if (t < 128) { dcnt[t] = 0; kcur[t] = 0; }
    sorted[t] = 0;
    if (t < 8) sorted[TCAP + t] = 0;
    if (t < 128) {
        const int sr = t >> 3;
        const int sp = t & 7;
        const uint4* s4 = (const uint4*)(xin + (size_t)(node0 + sr) * 128 + sp * 16);
        uint4 r0 = s4[0], r1 = s4[1];
        uint4* d = (uint4*)&As0[sr][sp * 16];
        d[0] = r0; d[1] = r1;
    }
    const int nraw = gcnt[blockIdx.x];
    const int n = nraw < TCAP ? nraw : TCAP;
    unsigned rec = 0;
    if (t < n) rec = gbin[(size_t)blockIdx.x * TCAP + t];
    __syncthreads();   // bar1: zeros visible

    // ---- P1: per-key histogram ----
    if (t < n) atomicAdd(&dcnt[rec & 127], 1);
    __syncthreads();   // bar2

    // ---- P2: wave-0 exclusive scan over 128 keys ----
    if (t < 64) {
        int d0 = dcnt[2 * t], d1 = dcnt[2 * t + 1];
        int s = d0 + d1;
        int inc = s;
#pragma unroll
        for (int off = 1; off < 64; off <<= 1) {
            int y = __shfl_up(inc, off, 64);
            if (t >= off) inc += y;
        }
        int excl = inc - s;
        kbeg[2 * t]     = excl;
        kbeg[2 * t + 1] = excl + d0;
    }
    __syncthreads();   // bar3

    // ---- P3: scatter-sort records into per-key src lists ----
    if (t < n) {
        int key = rec & 127;
        int pos = atomicAdd(&kcur[key], 1);
        sorted[kbeg[key] + pos] = (unsigned short)(rec >> 7);
    }
    __syncthreads();   // bar4: sorted/dcnt/kbeg ready

    // ---- P4: pipelined gather, one chain per (node, rel), 4 lanes ----
    {
        const int key = t >> 2;        // nl*8 + rel
        const int q   = t & 3;         // 32-feat quarter
        const int rel = key & 7;
        const int nl  = key >> 3;

        const int beg = kbeg[key];
        const int deg = dcnt[key];
        const int end = beg + deg;

        const unsigned short* bx = xin + q * 32;
        float a[32];
#pragma unroll
        for (int i = 0; i < 32; ++i) a[i] = 0.f;

        // preload edges beg, beg+1 (safe: sorted is zero-padded; deg<2 over-
        // reads land on row 0 which stays L1-hot)
        int j = beg;
        int sA = sorted[j];
        int sB = sorted[j + 1];
        const uint4* pA = (const uint4*)(bx + (size_t)sA * 128);
        const uint4* pB = (const uint4*)(bx + (size_t)sB * 128);
        uint4 A0 = pA[0], A1 = pA[1], A2 = pA[2], A3 = pA[3];
        uint4 B0 = pB[0], B1 = pB[1], B2 = pB[2], B3 = pB[3];

        for (; j + 1 < end; j += 2) {
            // prefetch next group while current accumulates
            int sC = sorted[j + 2];
            int sD = sorted[j + 3];
            const uint4* pC = (const uint4*)(bx + (size_t)sC * 128);
            const uint4* pD = (const uint4*)(bx + (size_t)sD * 128);
            uint4 C0 = pC[0], C1 = pC[1], C2 = pC[2], C3 = pC[3];
            uint4 D0 = pD[0], D1 = pD[1], D2 = pD[2], D3 = pD[3];

            acc16(a, A0, A1);
            acc16(a + 16, A2, A3);
            acc16(a, B0, B1);
            acc16(a + 16, B2, B3);

            A0 = C0; A1 = C1; A2 = C2; A3 = C3;
            B0 = D0; B1 = D1; B2 = D2; B3 = D3;
        }
        if (j < end) {   // odd tail: A holds edge j
            acc16(a, A0, A1);
            acc16(a + 16, A2, A3);
        }

        float scl = 1.f / (float)(deg > 1 ? deg : 1);
        unsigned int pk[16];
#pragma unroll
        for (int i = 0; i < 16; ++i)
            pk[i] = (unsigned int)f2bf(a[i * 2] * scl) |
                    ((unsigned int)f2bf(a[i * 2 + 1] * scl) << 16);
        // swizzled stores: row-local granule (q*4+i) ^ rel
        uint4* G = (uint4*)&As[rel][nl][0];
        const int g0 = q * 4;
        G[(g0 + 0) ^ rel] = make_uint4(pk[0],  pk[1],  pk[2],  pk[3]);
        G[(g0 + 1) ^ rel] = make_uint4(pk[4],  pk[5],  pk[6],  pk[7]);
        G[(g0 + 2) ^ rel] = make_uint4(pk[8],  pk[9],  pk[10], pk[11]);
        G[(g0 + 3) ^ rel] = make_uint4(pk[12], pk[13], pk[14], pk[15]);
    }

    __syncthreads();   // bar5: all 9 A slabs ready

    // ---- P5: MFMA, wave w owns col-tile w ----
    const int lane = t & 63;
    const int w = t >> 6;
    if (w >= NBt) return;            // FOUT=64: waves 4-7 done (no barriers after)
    const int quad = lane >> 4;
    const int tc = lane & 15;

    f32x4 acc = (f32x4){0.f, 0.f, 0.f, 0.f};
    const bf16x8* Bp = (const bf16x8*)WtP;

#pragma unroll
    for (int seg = 0; seg < 9; ++seg) {
        const uint4* Ag = (seg == 0) ? (const uint4*)&As0[tc][0]
                                     : (const uint4*)&As[seg - 1][tc][0];
        const int s = (seg == 0) ? 0 : (seg - 1);   // un-swizzle (uniform per instr)
#pragma unroll
        for (int kk = 0; kk < 4; ++kk) {
            bf16x8 af = *(const bf16x8*)(Ag + (((kk << 2) + quad) ^ s));
            bf16x8 bf = Bp[((seg * 4 + kk) * NBt + w) * 64 + lane];
            acc = __builtin_amdgcn_mfma_f32_16x16x32_bf16(af, bf, acc, 0, 0, 0);
        }
    }

    // epilogue: D layout col = lane&15, row = quad*4 + reg
    const int col = w * 16 + tc;
    const float bs = bias[col];
#pragma unroll
    for (int i = 0; i < 4; ++i) {
        int r = node0 + quad * 4 + i;
        float v = acc[i] + bs;
        if (RELU) v = fmaxf(v, 0.f);
        if (OUT_BF16) outb[(size_t)r * FOUT + col] = f2bf(v);
        else          outf[(size_t)r * FOUT + col] = v;
    }
}

// ---------------- launch ----------------

extern "C" void kernel_launch(void* const* d_in, const int* in_sizes, int n_in,
                              void* d_out, int out_size, void* d_ws, size_t ws_size,
                              hipStream_t stream) {
    const float* x     = (const float*)d_in[0];
    const int*   ei    = (const int*)d_in[1];  // [2][E]: row0=src, row1=dst
    const int*   et    = (const int*)d_in[2];  // [E]
    const float* W1    = (const float*)d_in[3];
    const float* root1 = (const float*)d_in[4];
    const float* b1    = (const float*)d_in[5];
    const float* W2    = (const float*)d_in[6];
    const float* root2 = (const float*)d_in[7];
    const float* b2    = (const float*)d_in[8];
    float* out = (float*)d_out;

    int* ws = (int*)d_ws;
    int* gcur = ws;                                   // [3200] (TNBKT padded)
    unsigned* gbin = (unsigned*)(gcur + 3200);        // TNBKT*TCAP u32 = 6.4 MB
    unsigned short* xb  = (unsigned short*)(gbin + (size_t)TNBKT * TCAP); // 12.8 MB
    unsigned short* hb  = xb + (size_t)N_NODES * 128;                     // 12.8 MB
    unsigned short* Wt1 = hb + (size_t)N_NODES * 128;                     // 288 KB
    unsigned short* Wt2 = Wt1 + W1_ELEMS;                                 // 144 KB
    // total ws usage ~32.5 MB (ws = 256 MiB)

    const int* esrc = ei;
    const int* edst = ei + N_EDGES;

    // memset + 3 kernels: prep (bin ∥ convert) -> fused x2
    hipMemsetAsync(gcur, 0, 3200 * sizeof(int), stream);
    k_prep<<<NB_PREP, 256, 0, stream>>>(esrc, edst, et, gcur, gbin,
                                        x, xb, root1, W1, root2, W2, Wt1, Wt2);

    const int NT = N_NODES / 16;  // 3125 exactly

    k_fused<128, true,  true ><<<NT, 512, 0, stream>>>(xb, Wt1, b1, gcur, gbin, hb, nullptr);
    k_fused<64,  false, false><<<NT, 512, 0, stream>>>(hb, Wt2, b2, gcur, gbin, nullptr, out);
}